// Round 6
// baseline (48.325 us; speedup 1.0000x reference)
//
#include <hip/hip_runtime.h>
#include <cstdint>
#include <cstddef>

static constexpr int HW_ = 16384;  // h*w
static constexpr int NB_ = 32;     // batch
static constexpr int NN_ = 64;     // n
static constexpr int BK_ = 64;     // k per staged LDS tile

typedef short bfrag  __attribute__((ext_vector_type(8)));  // 8 bf16 (4 VGPRs)
typedef float f32x4  __attribute__((ext_vector_type(4)));  // MFMA accumulator

// fp32 -> bf16, round-to-nearest-even
__device__ __forceinline__ unsigned short f2bf_rne(float x) {
    unsigned u = __builtin_bit_cast(unsigned, x);
    return (unsigned short)((u + 0x7FFFu + ((u >> 16) & 1u)) >> 16);
}

// XOR-swizzled bf16-element index in a row-major [64][BK_=64] bf16 tile
// (128 B rows). byte ^= (row&7)<<4. Same involution on write+read.
__device__ __forceinline__ int swz(int row, int k) {
    int byte = (row << 7) + (k << 1);
    byte ^= (row & 7) << 4;
    return byte >> 1;
}

__global__ __launch_bounds__(256) void gram_kernel(const float* __restrict__ masks,
                                                   float* __restrict__ gram_part,
                                                   float* __restrict__ s_part,
                                                   unsigned int* __restrict__ counters,
                                                   int NC, int KC) {
    // zero the epilogue's 17 sync counters (visible at kernel end, stream order)
    if (blockIdx.x == 0 && threadIdx.x < 17) counters[threadIdx.x] = 0u;

    __shared__ __align__(16) unsigned short lds[2][NN_ * BK_];  // 2 x 8 KiB bf16
    const int bx = blockIdx.x;
    const int b  = bx / NC;
    const int c  = bx - b * NC;
    const int t  = threadIdx.x;        // 256 threads = 4 waves
    const int l  = t & 63;
    const int w  = t >> 6;             // wave id: owns output rows [16w,16w+16)
    const int lrow = t >> 4;           // staging row base 0..15
    const int lk4  = t & 15;           // staging float4 index along k
    const float* mb = masks + (size_t)b * (NN_ * HW_) + (size_t)c * KC;
    const int NT = KC / BK_;           // even for all power-of-2 NC <= 128

    f32x4 acc[4];
#pragma unroll
    for (int cb = 0; cb < 4; ++cb) acc[cb] = (f32x4){0.f, 0.f, 0.f, 0.f};
    float sreg[4] = {0.f, 0.f, 0.f, 0.f};
    float4 ldA[4], ldB[4];             // two named staging sets (rule #20: no
                                       // runtime-indexed register arrays)

    auto stage_load = [&](float4* ld, int tt) {
        const float* src = mb + tt * BK_ + lk4 * 4;
#pragma unroll
        for (int p = 0; p < 4; ++p)
            ld[p] = *reinterpret_cast<const float4*>(src + (size_t)(lrow + 16 * p) * HW_);
    };
    auto stage_write = [&](unsigned short* buf, const float4* ld) {
#pragma unroll
        for (int p = 0; p < 4; ++p) {
            const float m0 = fmaxf(0.f, (ld[p].x + 1.f) * 0.5f);
            const float m1 = fmaxf(0.f, (ld[p].y + 1.f) * 0.5f);
            const float m2 = fmaxf(0.f, (ld[p].z + 1.f) * 0.5f);
            const float m3 = fmaxf(0.f, (ld[p].w + 1.f) * 0.5f);
            sreg[p] += (m0 + m1) + (m2 + m3);
            const ushort4 pk = make_ushort4(f2bf_rne(m0), f2bf_rne(m1),
                                            f2bf_rne(m2), f2bf_rne(m3));
            *reinterpret_cast<ushort4*>(&buf[swz(lrow + 16 * p, lk4 * 4)]) = pk;
        }
    };
    auto compute = [&](const unsigned short* buf) {
#pragma unroll
        for (int ks = 0; ks < BK_; ks += 32) {
            const int kb = ks + ((l >> 4) << 3);
            const bfrag a = *reinterpret_cast<const bfrag*>(&buf[swz((w << 4) + (l & 15), kb)]);
#pragma unroll
            for (int cb = 0; cb < 4; ++cb) {
                const bfrag bb = *reinterpret_cast<const bfrag*>(&buf[swz((cb << 4) + (l & 15), kb)]);
                acc[cb] = __builtin_amdgcn_mfma_f32_16x16x32_bf16(a, bb, acc[cb], 0, 0, 0);
            }
        }
    };

    // 2-deep pipeline: tile tt+2's loads are issued one FULL iteration before
    // their stage_write consumes them (~2400cy cover vs ~900cy HBM latency).
    // Sets alternate with tile parity: even tiles ldA, odd tiles ldB.
    stage_load(ldA, 0);
    stage_write(lds[0], ldA);          // waits ldA
    if (NT > 1) stage_load(ldB, 1);
    __syncthreads();
    for (int tt = 0; tt < NT; tt += 2) {
        // even tile tt: compute lds[0]; write tile tt+1 into lds[1]; load tile tt+2
        if (tt + 2 < NT) stage_load(ldA, tt + 2);   // issue first (counted vmcnt)
        if (tt + 1 < NT) stage_write(lds[1], ldB);  // waits ldB (issued 1 iter ago)
        compute(lds[0]);
        __syncthreads();
        if (tt + 1 < NT) {
            // odd tile tt+1: compute lds[1]; write tile tt+2 into lds[0]; load tile tt+3
            if (tt + 3 < NT) stage_load(ldB, tt + 3);
            if (tt + 2 < NT) stage_write(lds[0], ldA);
            compute(lds[1]);
            __syncthreads();
        }
    }

    // C/D layout: col = lane&15, row = (lane>>4)*4 + reg
    float* gp = gram_part + (size_t)(c * NB_ + b) * (NN_ * NN_);
#pragma unroll
    for (int cb = 0; cb < 4; ++cb)
#pragma unroll
        for (int r = 0; r < 4; ++r) {
            const int i = (w << 4) + ((l >> 4) << 2) + r;
            const int j = (cb << 4) + (l & 15);
            gp[i * NN_ + j] = acc[cb][r];
        }
#pragma unroll
    for (int p = 0; p < 4; ++p) {
        float v = sreg[p];
        v += __shfl_xor(v, 1, 64);
        v += __shfl_xor(v, 2, 64);
        v += __shfl_xor(v, 4, 64);
        v += __shfl_xor(v, 8, 64);
        if ((l & 15) == 0)
            s_part[(size_t)c * (NB_ * NN_) + b * NN_ + (lrow + 16 * p)] = v;
    }
}

// Fused epilogue: phase 1 (per (b,ijc) block): c-reduce gram partials + s_part,
// write wq = g/min(si,sj). Last block per ijc (counter[ijc]) does phase 2:
// b-mean -> cr -> mask -> num/den[ijc]. Last ijc (counter[16]) writes out.
// All data reductions are fixed-order (atomics only gate WHO runs) -> deterministic.
__global__ __launch_bounds__(256) void epilogue_kernel(const float* __restrict__ gram_part,
                                                       const float* __restrict__ s_part,
                                                       const int* __restrict__ nodes,
                                                       float* __restrict__ wq,
                                                       float* __restrict__ num_part,
                                                       float* __restrict__ den_part,
                                                       unsigned int* __restrict__ counters,
                                                       float* __restrict__ out, int NC) {
    __shared__ float s_loc[NN_];
    __shared__ float red[8];
    __shared__ int flag;
    const int b   = blockIdx.x;                  // 0..31
    const int ijc = blockIdx.y;                  // 0..15
    const int t   = threadIdx.x;
    const int ij  = ijc * 256 + t;

    if (t < NN_) {
        float v = 0.f;
        for (int c = 0; c < NC; ++c)
            v += s_part[(size_t)c * (NB_ * NN_) + b * NN_ + t];
        s_loc[t] = v;
    }
    __syncthreads();
    float g = 0.f;
#pragma unroll 8
    for (int c = 0; c < NC; ++c)
        g += gram_part[(size_t)(c * NB_ + b) * (NN_ * NN_) + ij];
    const int i = ij >> 6, j = ij & 63;
    wq[(size_t)b * (NN_ * NN_) + ij] = g / fminf(s_loc[i], s_loc[j]);

    __syncthreads();  // all wq stores of this block precede thread0's release-RMW
    if (t == 0) {
        const unsigned old = __hip_atomic_fetch_add(&counters[ijc], 1u, __ATOMIC_ACQ_REL,
                                                    __HIP_MEMORY_SCOPE_AGENT);
        flag = (old == (unsigned)(NB_ - 1));
    }
    __syncthreads();
    if (!flag) return;

    // ---- phase 2: finalize this ijc column (reads all 32 b's wq: 32 KB)
    float acc = 0.f;
#pragma unroll
    for (int b2 = 0; b2 < NB_; ++b2)
        acc += wq[(size_t)b2 * (NN_ * NN_) + ij];
    const float cr = acc * (1.0f / NB_);

    const int ni = nodes[i];
    const int nj = nodes[j];
    const int ti = (ni < 7) ? 0 : ((ni < 9) ? 1 : 2);
    const int tj = (nj < 7) ? 0 : ((nj < 9) ? 1 : 2);
    const bool has_f = (ti == 1) || (tj == 1);
    const bool has_a = (ti == 2) || (tj == 2);
    const bool include = !(has_f && !has_a);
    const float beta = ((ti == 2) != (tj == 2)) ? 1.f : 0.f;
    const float wgt = (include && (j > i)) ? 1.f : 0.f;

    float num = wgt * fabsf(beta - cr);
    float den = wgt;
#pragma unroll
    for (int off = 32; off >= 1; off >>= 1) {
        num += __shfl_xor(num, off, 64);
        den += __shfl_xor(den, off, 64);
    }
    const int wave = t >> 6;
    const int lane = t & 63;
    if (lane == 0) { red[wave] = num; red[4 + wave] = den; }
    __syncthreads();
    if (t == 0) {
        num_part[ijc] = red[0] + red[1] + red[2] + red[3];
        den_part[ijc] = red[4] + red[5] + red[6] + red[7];
        const unsigned old = __hip_atomic_fetch_add(&counters[16], 1u, __ATOMIC_ACQ_REL,
                                                    __HIP_MEMORY_SCOPE_AGENT);
        flag = (old == 15u);
    }
    __syncthreads();
    if (flag && t < 64) {
        float n16 = (t < 16) ? num_part[t] : 0.f;
        float d16 = (t < 16) ? den_part[t] : 0.f;
#pragma unroll
        for (int off = 8; off >= 1; off >>= 1) {
            n16 += __shfl_xor(n16, off, 64);
            d16 += __shfl_xor(d16, off, 64);
        }
        if (t == 0) out[0] = n16 / d16;
    }
}

extern "C" void kernel_launch(void* const* d_in, const int* in_sizes, int n_in,
                              void* d_out, int out_size, void* d_ws, size_t ws_size,
                              hipStream_t stream) {
    const float* masks = (const float*)d_in[0];
    const int* nodes = (const int*)d_in[1];   // harness passes integers as int32
    float* out = (float*)d_out;

    const size_t ws_floats = ws_size / sizeof(float);
    int NC = 16;
    while (NC > 1) {
        const size_t need = (size_t)NC * NB_ * NN_ * NN_   // gram partials
                          + (size_t)NC * NB_ * NN_         // s partials
                          + (size_t)NB_ * NN_ * NN_        // wq
                          + 2 * 16 + 17;                   // partials + counters
        if (need <= ws_floats) break;
        NC >>= 1;
    }
    const int KC = HW_ / NC;

    float* gram_part = (float*)d_ws;
    float* s_part    = gram_part + (size_t)NC * NB_ * NN_ * NN_;
    float* wq        = s_part    + (size_t)NC * NB_ * NN_;
    float* num_part  = wq        + (size_t)NB_ * NN_ * NN_;
    float* den_part  = num_part  + 16;
    unsigned int* counters = (unsigned int*)(den_part + 16);

    gram_kernel<<<NB_ * NC, 256, 0, stream>>>(masks, gram_part, s_part, counters, NC, KC);
    epilogue_kernel<<<dim3(NB_, (NN_ * NN_) / 256), 256, 0, stream>>>(
        gram_part, s_part, nodes, wq, num_part, den_part, counters, out, NC);
}

// Round 7
// 47.710 us; speedup vs baseline: 1.0129x; 1.0129x over previous
//
#include <hip/hip_runtime.h>
#include <cstdint>
#include <cstddef>

static constexpr int HW_ = 16384;  // h*w
static constexpr int NB_ = 32;     // batch
static constexpr int NN_ = 64;     // n
static constexpr int BK_ = 64;     // k per staged LDS tile

typedef short bfrag  __attribute__((ext_vector_type(8)));  // 8 bf16 (4 VGPRs)
typedef float f32x4  __attribute__((ext_vector_type(4)));  // MFMA accumulator

// fp32 -> bf16, round-to-nearest-even
__device__ __forceinline__ unsigned short f2bf_rne(float x) {
    unsigned u = __builtin_bit_cast(unsigned, x);
    return (unsigned short)((u + 0x7FFFu + ((u >> 16) & 1u)) >> 16);
}

// XOR-swizzled bf16-element index in a row-major [64][BK_=64] bf16 tile
// (128 B rows). byte ^= (row&7)<<4. Same involution on write+read.
__device__ __forceinline__ int swz(int row, int k) {
    int byte = (row << 7) + (k << 1);
    byte ^= (row & 7) << 4;
    return byte >> 1;
}

// ROUND-5 PROVEN STRUCTURE (do not reorder): stage_load(next) -> compute(cur)
// -> stage_write(next). compute-first keeps MFMA/ds_read ahead of the ds_write
// burst in program order (round 6 inverted this and lost 6 us).
__global__ __launch_bounds__(256) void gram_kernel(const float* __restrict__ masks,
                                                   float* __restrict__ gram_part,
                                                   float* __restrict__ s_part,
                                                   unsigned int* __restrict__ counters,
                                                   int NC, int KC) {
    // zero the epilogue's 17 sync counters (visible at kernel end, stream order)
    if (blockIdx.x == 0 && threadIdx.x < 17) counters[threadIdx.x] = 0u;

    __shared__ __align__(16) unsigned short lds[2][NN_ * BK_];  // 2 x 8 KiB bf16
    const int bx = blockIdx.x;
    const int b  = bx / NC;
    const int c  = bx - b * NC;
    const int t  = threadIdx.x;        // 256 threads = 4 waves
    const int l  = t & 63;
    const int w  = t >> 6;             // wave id: owns output rows [16w,16w+16)
    const int lrow = t >> 4;           // staging row base 0..15
    const int lk4  = t & 15;           // staging float4 index along k
    const float* mb = masks + (size_t)b * (NN_ * HW_) + (size_t)c * KC;
    const int NT = KC / BK_;

    f32x4 acc[4];
#pragma unroll
    for (int cb = 0; cb < 4; ++cb) acc[cb] = (f32x4){0.f, 0.f, 0.f, 0.f};
    float sreg[4] = {0.f, 0.f, 0.f, 0.f};
    float4 ld[4];

    auto stage_load = [&](int tt) {
        const float* src = mb + tt * BK_ + lk4 * 4;
#pragma unroll
        for (int p = 0; p < 4; ++p)
            ld[p] = *reinterpret_cast<const float4*>(src + (size_t)(lrow + 16 * p) * HW_);
    };
    auto stage_write = [&](unsigned short* buf) {
#pragma unroll
        for (int p = 0; p < 4; ++p) {
            const float m0 = fmaxf(0.f, (ld[p].x + 1.f) * 0.5f);
            const float m1 = fmaxf(0.f, (ld[p].y + 1.f) * 0.5f);
            const float m2 = fmaxf(0.f, (ld[p].z + 1.f) * 0.5f);
            const float m3 = fmaxf(0.f, (ld[p].w + 1.f) * 0.5f);
            sreg[p] += (m0 + m1) + (m2 + m3);
            const ushort4 pk = make_ushort4(f2bf_rne(m0), f2bf_rne(m1),
                                            f2bf_rne(m2), f2bf_rne(m3));
            *reinterpret_cast<ushort4*>(&buf[swz(lrow + 16 * p, lk4 * 4)]) = pk;
        }
    };
    auto compute = [&](const unsigned short* buf) {
#pragma unroll
        for (int ks = 0; ks < BK_; ks += 32) {
            const int kb = ks + ((l >> 4) << 3);
            const bfrag a = *reinterpret_cast<const bfrag*>(&buf[swz((w << 4) + (l & 15), kb)]);
#pragma unroll
            for (int cb = 0; cb < 4; ++cb) {
                const bfrag bb = *reinterpret_cast<const bfrag*>(&buf[swz((cb << 4) + (l & 15), kb)]);
                acc[cb] = __builtin_amdgcn_mfma_f32_16x16x32_bf16(a, bb, acc[cb], 0, 0, 0);
            }
        }
    };

    stage_load(0);
    stage_write(lds[0]);
    __syncthreads();
    for (int tt = 0; tt < NT; ++tt) {
        const int cur = tt & 1;
        const bool more = (tt + 1 < NT);
        if (more) stage_load(tt + 1);         // issue early
        compute(lds[cur]);                    // hide HBM latency under MFMA
        if (more) stage_write(lds[cur ^ 1]);  // write late
        __syncthreads();
    }

    // C/D layout: col = lane&15, row = (lane>>4)*4 + reg
    float* gp = gram_part + (size_t)(c * NB_ + b) * (NN_ * NN_);
#pragma unroll
    for (int cb = 0; cb < 4; ++cb)
#pragma unroll
        for (int r = 0; r < 4; ++r) {
            const int i = (w << 4) + ((l >> 4) << 2) + r;
            const int j = (cb << 4) + (l & 15);
            gp[i * NN_ + j] = acc[cb][r];
        }
#pragma unroll
    for (int p = 0; p < 4; ++p) {
        float v = sreg[p];
        v += __shfl_xor(v, 1, 64);
        v += __shfl_xor(v, 2, 64);
        v += __shfl_xor(v, 4, 64);
        v += __shfl_xor(v, 8, 64);
        if ((l & 15) == 0)
            s_part[(size_t)c * (NB_ * NN_) + b * NN_ + (lrow + 16 * p)] = v;
    }
}

// Fused epilogue (round-6, passing): phase 1 per (b,ijc): c-reduce gram
// partials + s_part, write wq = g/min(si,sj). Last block per ijc does phase 2:
// b-mean -> cr -> mask -> num/den[ijc]. Last ijc writes out. All data
// reductions fixed-order (atomics only gate WHO runs) -> deterministic.
__global__ __launch_bounds__(256) void epilogue_kernel(const float* __restrict__ gram_part,
                                                       const float* __restrict__ s_part,
                                                       const int* __restrict__ nodes,
                                                       float* __restrict__ wq,
                                                       float* __restrict__ num_part,
                                                       float* __restrict__ den_part,
                                                       unsigned int* __restrict__ counters,
                                                       float* __restrict__ out, int NC) {
    __shared__ float s_loc[NN_];
    __shared__ float red[8];
    __shared__ int flag;
    const int b   = blockIdx.x;                  // 0..31
    const int ijc = blockIdx.y;                  // 0..15
    const int t   = threadIdx.x;
    const int ij  = ijc * 256 + t;

    if (t < NN_) {
        float v = 0.f;
        for (int c = 0; c < NC; ++c)
            v += s_part[(size_t)c * (NB_ * NN_) + b * NN_ + t];
        s_loc[t] = v;
    }
    __syncthreads();
    float g = 0.f;
#pragma unroll 8
    for (int c = 0; c < NC; ++c)
        g += gram_part[(size_t)(c * NB_ + b) * (NN_ * NN_) + ij];
    const int i = ij >> 6, j = ij & 63;
    wq[(size_t)b * (NN_ * NN_) + ij] = g / fminf(s_loc[i], s_loc[j]);

    __syncthreads();  // all wq stores of this block precede thread0's release-RMW
    if (t == 0) {
        const unsigned old = __hip_atomic_fetch_add(&counters[ijc], 1u, __ATOMIC_ACQ_REL,
                                                    __HIP_MEMORY_SCOPE_AGENT);
        flag = (old == (unsigned)(NB_ - 1));
    }
    __syncthreads();
    if (!flag) return;

    // ---- phase 2: finalize this ijc column (reads all 32 b's wq: 32 KB, L2-hot)
    float acc = 0.f;
#pragma unroll
    for (int b2 = 0; b2 < NB_; ++b2)
        acc += wq[(size_t)b2 * (NN_ * NN_) + ij];
    const float cr = acc * (1.0f / NB_);

    const int ni = nodes[i];
    const int nj = nodes[j];
    const int ti = (ni < 7) ? 0 : ((ni < 9) ? 1 : 2);
    const int tj = (nj < 7) ? 0 : ((nj < 9) ? 1 : 2);
    const bool has_f = (ti == 1) || (tj == 1);
    const bool has_a = (ti == 2) || (tj == 2);
    const bool include = !(has_f && !has_a);
    const float beta = ((ti == 2) != (tj == 2)) ? 1.f : 0.f;
    const float wgt = (include && (j > i)) ? 1.f : 0.f;

    float num = wgt * fabsf(beta - cr);
    float den = wgt;
#pragma unroll
    for (int off = 32; off >= 1; off >>= 1) {
        num += __shfl_xor(num, off, 64);
        den += __shfl_xor(den, off, 64);
    }
    const int wave = t >> 6;
    const int lane = t & 63;
    if (lane == 0) { red[wave] = num; red[4 + wave] = den; }
    __syncthreads();
    if (t == 0) {
        num_part[ijc] = red[0] + red[1] + red[2] + red[3];
        den_part[ijc] = red[4] + red[5] + red[6] + red[7];
        const unsigned old = __hip_atomic_fetch_add(&counters[16], 1u, __ATOMIC_ACQ_REL,
                                                    __HIP_MEMORY_SCOPE_AGENT);
        flag = (old == 15u);
    }
    __syncthreads();
    if (flag && t < 64) {
        float n16 = (t < 16) ? num_part[t] : 0.f;
        float d16 = (t < 16) ? den_part[t] : 0.f;
#pragma unroll
        for (int off = 8; off >= 1; off >>= 1) {
            n16 += __shfl_xor(n16, off, 64);
            d16 += __shfl_xor(d16, off, 64);
        }
        if (t == 0) out[0] = n16 / d16;
    }
}

extern "C" void kernel_launch(void* const* d_in, const int* in_sizes, int n_in,
                              void* d_out, int out_size, void* d_ws, size_t ws_size,
                              hipStream_t stream) {
    const float* masks = (const float*)d_in[0];
    const int* nodes = (const int*)d_in[1];   // harness passes integers as int32
    float* out = (float*)d_out;

    const size_t ws_floats = ws_size / sizeof(float);
    int NC = 16;
    while (NC > 1) {
        const size_t need = (size_t)NC * NB_ * NN_ * NN_   // gram partials
                          + (size_t)NC * NB_ * NN_         // s partials
                          + (size_t)NB_ * NN_ * NN_        // wq
                          + 2 * 16 + 17;                   // partials + counters
        if (need <= ws_floats) break;
        NC >>= 1;
    }
    const int KC = HW_ / NC;

    float* gram_part = (float*)d_ws;
    float* s_part    = gram_part + (size_t)NC * NB_ * NN_ * NN_;
    float* wq        = s_part    + (size_t)NC * NB_ * NN_;
    float* num_part  = wq        + (size_t)NB_ * NN_ * NN_;
    float* den_part  = num_part  + 16;
    unsigned int* counters = (unsigned int*)(den_part + 16);

    gram_kernel<<<NB_ * NC, 256, 0, stream>>>(masks, gram_part, s_part, counters, NC, KC);
    epilogue_kernel<<<dim3(NB_, (NN_ * NN_) / 256), 256, 0, stream>>>(
        gram_part, s_part, nodes, wq, num_part, den_part, counters, out, NC);
}

// Round 8
// 37.645 us; speedup vs baseline: 1.2837x; 1.2674x over previous
//
#include <hip/hip_runtime.h>
#include <cstdint>
#include <cstddef>

static constexpr int HW_ = 16384;  // h*w
static constexpr int NB_ = 32;     // batch
static constexpr int NN_ = 64;     // n
static constexpr int BK_ = 64;     // k per staged LDS tile

typedef short bfrag  __attribute__((ext_vector_type(8)));  // 8 bf16 (4 VGPRs)
typedef float f32x4  __attribute__((ext_vector_type(4)));  // MFMA accumulator

// fp32 -> bf16, round-to-nearest-even
__device__ __forceinline__ unsigned short f2bf_rne(float x) {
    unsigned u = __builtin_bit_cast(unsigned, x);
    return (unsigned short)((u + 0x7FFFu + ((u >> 16) & 1u)) >> 16);
}

// XOR-swizzled bf16-element index in a row-major [64][BK_=64] bf16 tile
// (128 B rows). byte ^= (row&7)<<4. Same involution on write+read.
__device__ __forceinline__ int swz(int row, int k) {
    int byte = (row << 7) + (k << 1);
    byte ^= (row & 7) << 4;
    return byte >> 1;
}

// ROUND-5 PROVEN STRUCTURE: stage_load(next) -> compute(cur) -> stage_write(next).
__global__ __launch_bounds__(256) void gram_kernel(const float* __restrict__ masks,
                                                   float* __restrict__ gram_part,
                                                   float* __restrict__ s_part,
                                                   unsigned int* __restrict__ counter,
                                                   int NC, int KC) {
    // zero loss2's sync counter (visible at kernel end, stream order) — kills
    // the separate hipMemsetAsync dispatch
    if (blockIdx.x == 0 && threadIdx.x == 0) *counter = 0u;

    __shared__ __align__(16) unsigned short lds[2][NN_ * BK_];  // 2 x 8 KiB bf16
    const int bx = blockIdx.x;
    const int b  = bx / NC;
    const int c  = bx - b * NC;
    const int t  = threadIdx.x;        // 256 threads = 4 waves
    const int l  = t & 63;
    const int w  = t >> 6;             // wave id: owns output rows [16w,16w+16)
    const int lrow = t >> 4;           // staging row base 0..15
    const int lk4  = t & 15;           // staging float4 index along k
    const float* mb = masks + (size_t)b * (NN_ * HW_) + (size_t)c * KC;
    const int NT = KC / BK_;

    f32x4 acc[4];
#pragma unroll
    for (int cb = 0; cb < 4; ++cb) acc[cb] = (f32x4){0.f, 0.f, 0.f, 0.f};
    float sreg[4] = {0.f, 0.f, 0.f, 0.f};
    float4 ld[4];

    auto stage_load = [&](int tt) {
        const float* src = mb + tt * BK_ + lk4 * 4;
#pragma unroll
        for (int p = 0; p < 4; ++p)
            ld[p] = *reinterpret_cast<const float4*>(src + (size_t)(lrow + 16 * p) * HW_);
    };
    auto stage_write = [&](unsigned short* buf) {
#pragma unroll
        for (int p = 0; p < 4; ++p) {
            const float m0 = fmaxf(0.f, (ld[p].x + 1.f) * 0.5f);
            const float m1 = fmaxf(0.f, (ld[p].y + 1.f) * 0.5f);
            const float m2 = fmaxf(0.f, (ld[p].z + 1.f) * 0.5f);
            const float m3 = fmaxf(0.f, (ld[p].w + 1.f) * 0.5f);
            sreg[p] += (m0 + m1) + (m2 + m3);
            const ushort4 pk = make_ushort4(f2bf_rne(m0), f2bf_rne(m1),
                                            f2bf_rne(m2), f2bf_rne(m3));
            *reinterpret_cast<ushort4*>(&buf[swz(lrow + 16 * p, lk4 * 4)]) = pk;
        }
    };
    auto compute = [&](const unsigned short* buf) {
#pragma unroll
        for (int ks = 0; ks < BK_; ks += 32) {
            const int kb = ks + ((l >> 4) << 3);
            const bfrag a = *reinterpret_cast<const bfrag*>(&buf[swz((w << 4) + (l & 15), kb)]);
#pragma unroll
            for (int cb = 0; cb < 4; ++cb) {
                const bfrag bb = *reinterpret_cast<const bfrag*>(&buf[swz((cb << 4) + (l & 15), kb)]);
                acc[cb] = __builtin_amdgcn_mfma_f32_16x16x32_bf16(a, bb, acc[cb], 0, 0, 0);
            }
        }
    };

    stage_load(0);
    stage_write(lds[0]);
    __syncthreads();
    for (int tt = 0; tt < NT; ++tt) {
        const int cur = tt & 1;
        const bool more = (tt + 1 < NT);
        if (more) stage_load(tt + 1);         // issue early
        compute(lds[cur]);                    // hide HBM latency under MFMA
        if (more) stage_write(lds[cur ^ 1]);  // write late
        __syncthreads();
    }

    // C/D layout: col = lane&15, row = (lane>>4)*4 + reg
    float* gp = gram_part + (size_t)(c * NB_ + b) * (NN_ * NN_);
#pragma unroll
    for (int cb = 0; cb < 4; ++cb)
#pragma unroll
        for (int r = 0; r < 4; ++r) {
            const int i = (w << 4) + ((l >> 4) << 2) + r;
            const int j = (cb << 4) + (l & 15);
            gp[i * NN_ + j] = acc[cb][r];
        }
#pragma unroll
    for (int p = 0; p < 4; ++p) {
        float v = sreg[p];
        v += __shfl_xor(v, 1, 64);
        v += __shfl_xor(v, 2, 64);
        v += __shfl_xor(v, 4, 64);
        v += __shfl_xor(v, 8, 64);
        if ((l & 15) == 0)
            s_part[(size_t)c * (NB_ * NN_) + b * NN_ + (lrow + 16 * p)] = v;
    }
}

// Epilogue stage 1 (round-5 proven; NO cross-block atomics): per (b, ijc),
// reduce gram partials over c (coalesced), reduce s_part over c into LDS,
// write wq = g/min(si,sj).
__global__ __launch_bounds__(256) void cr_weight_kernel(const float* __restrict__ gram_part,
                                                        const float* __restrict__ s_part,
                                                        float* __restrict__ wq, int NC) {
    __shared__ float s_loc[NN_];
    const int b = blockIdx.x;                        // 0..31
    if (threadIdx.x < NN_) {
        float v = 0.f;
        for (int c = 0; c < NC; ++c)
            v += s_part[(size_t)c * (NB_ * NN_) + b * NN_ + threadIdx.x];
        s_loc[threadIdx.x] = v;
    }
    __syncthreads();
    const int ij = blockIdx.y * 256 + threadIdx.x;   // 0..4095
    float g = 0.f;
#pragma unroll 8
    for (int c = 0; c < NC; ++c)
        g += gram_part[(size_t)(c * NB_ + b) * (NN_ * NN_) + ij];
    const int i = ij >> 6, j = ij & 63;
    wq[(size_t)b * (NN_ * NN_) + ij] = g / fminf(s_loc[i], s_loc[j]);
}

// Epilogue stage 2 (round-5 proven; final fused via last-block-done, only
// 16 RMWs total — the 512-RMW single-kernel fusion cost ~6 us in r6/r7
// from per-producer agent-scope L2 flushes): mean over b, mask, two-level
// reduce; last block combines the 16 partials.
__global__ __launch_bounds__(256) void loss2_kernel(const float* __restrict__ wq,
                                                    const int* __restrict__ nodes,
                                                    float* __restrict__ num_part,
                                                    float* __restrict__ den_part,
                                                    unsigned int* __restrict__ counter,
                                                    float* __restrict__ out) {
    __shared__ float red[8];
    __shared__ int is_last;
    const int ij = blockIdx.x * 256 + threadIdx.x;
    float acc = 0.f;
#pragma unroll
    for (int b = 0; b < NB_; ++b)
        acc += wq[(size_t)b * (NN_ * NN_) + ij];
    const float cr = acc * (1.0f / NB_);

    const int i = ij >> 6, j = ij & 63;
    const int ni = nodes[i];
    const int nj = nodes[j];
    const int ti = (ni < 7) ? 0 : ((ni < 9) ? 1 : 2);
    const int tj = (nj < 7) ? 0 : ((nj < 9) ? 1 : 2);
    const bool has_f = (ti == 1) || (tj == 1);
    const bool has_a = (ti == 2) || (tj == 2);
    const bool include = !(has_f && !has_a);
    const float beta = ((ti == 2) != (tj == 2)) ? 1.f : 0.f;
    const float wgt = (include && (j > i)) ? 1.f : 0.f;

    float num = wgt * fabsf(beta - cr);
    float den = wgt;
#pragma unroll
    for (int off = 32; off >= 1; off >>= 1) {
        num += __shfl_xor(num, off, 64);
        den += __shfl_xor(den, off, 64);
    }
    const int wave = threadIdx.x >> 6;
    const int lane = threadIdx.x & 63;
    if (lane == 0) { red[wave] = num; red[4 + wave] = den; }
    __syncthreads();
    if (threadIdx.x == 0) {
        const float bn = red[0] + red[1] + red[2] + red[3];
        const float bd = red[4] + red[5] + red[6] + red[7];
        __hip_atomic_store(&num_part[blockIdx.x], bn, __ATOMIC_RELAXED, __HIP_MEMORY_SCOPE_AGENT);
        __hip_atomic_store(&den_part[blockIdx.x], bd, __ATOMIC_RELAXED, __HIP_MEMORY_SCOPE_AGENT);
        const unsigned old = __hip_atomic_fetch_add(counter, 1u, __ATOMIC_ACQ_REL,
                                                    __HIP_MEMORY_SCOPE_AGENT);
        is_last = (old == (unsigned)(gridDim.x - 1));
    }
    __syncthreads();
    if (is_last && threadIdx.x < 64) {
        const int t = threadIdx.x;
        float n16 = 0.f, d16 = 0.f;
        if (t < 16) {
            n16 = __hip_atomic_load(&num_part[t], __ATOMIC_RELAXED, __HIP_MEMORY_SCOPE_AGENT);
            d16 = __hip_atomic_load(&den_part[t], __ATOMIC_RELAXED, __HIP_MEMORY_SCOPE_AGENT);
        }
#pragma unroll
        for (int off = 8; off >= 1; off >>= 1) {
            n16 += __shfl_xor(n16, off, 64);
            d16 += __shfl_xor(d16, off, 64);
        }
        if (t == 0) out[0] = n16 / d16;
    }
}

extern "C" void kernel_launch(void* const* d_in, const int* in_sizes, int n_in,
                              void* d_out, int out_size, void* d_ws, size_t ws_size,
                              hipStream_t stream) {
    const float* masks = (const float*)d_in[0];
    const int* nodes = (const int*)d_in[1];   // harness passes integers as int32
    float* out = (float*)d_out;

    const size_t ws_floats = ws_size / sizeof(float);
    int NC = 16;
    while (NC > 1) {
        const size_t need = (size_t)NC * NB_ * NN_ * NN_   // gram partials
                          + (size_t)NC * NB_ * NN_         // s partials
                          + (size_t)NB_ * NN_ * NN_        // wq
                          + 2 * 16 + 1;                    // partials + counter
        if (need <= ws_floats) break;
        NC >>= 1;
    }
    const int KC = HW_ / NC;

    float* gram_part = (float*)d_ws;
    float* s_part    = gram_part + (size_t)NC * NB_ * NN_ * NN_;
    float* wq        = s_part    + (size_t)NC * NB_ * NN_;
    float* num_part  = wq        + (size_t)NB_ * NN_ * NN_;
    float* den_part  = num_part  + 16;
    unsigned int* counter = (unsigned int*)(den_part + 16);

    gram_kernel<<<NB_ * NC, 256, 0, stream>>>(masks, gram_part, s_part, counter, NC, KC);
    cr_weight_kernel<<<dim3(NB_, (NN_ * NN_) / 256), 256, 0, stream>>>(gram_part, s_part, wq, NC);
    loss2_kernel<<<(NN_ * NN_) / 256, 256, 0, stream>>>(wq, nodes, num_part, den_part, counter, out);
}